// Round 1
// 85.064 us; speedup vs baseline: 1.6915x; 1.6915x over previous
//
#include <hip/hip_runtime.h>

#define S_TOK 8192
#define NB 8
#define HQ 32
#define HKV 8
#define DH 128
#define KK 128
#define DIM 4096

// ---------------- Kernel 1: importance = mean over heads ----------------
__global__ __launch_bounds__(256) void importance_kernel(const float* __restrict__ attn_w,
                                                         float* __restrict__ imp) {
    int i = blockIdx.x * 256 + threadIdx.x;     // over NB*S_TOK
    if (i >= NB * S_TOK) return;
    int b = i >> 13;            // /8192
    int s = i & (S_TOK - 1);
    const float* p = attn_w + (size_t)b * HQ * S_TOK + s;
    float acc = 0.f;
#pragma unroll
    for (int h = 0; h < HQ; ++h) acc += p[(size_t)h * S_TOK];
    imp[i] = acc * (1.0f / 32.0f);
}

// ---------------- Kernel 2: fused { per-batch top-128 (blocks 0..7) | q GEMV (blocks 8..8+4095) } ----
// top-k order: value descending, index ascending on ties (lax.top_k semantics).
__global__ __launch_bounds__(256) void topk_gemvq_kernel(const float* __restrict__ imp,
                                                         int* __restrict__ topk,
                                                         const float* __restrict__ Wq,
                                                         const float* __restrict__ hidden,
                                                         float* __restrict__ q) {
    __shared__ __align__(16) unsigned mb[S_TOK];   // 32 KB mapped bits
    __shared__ __align__(16) int hist[256];
    __shared__ unsigned sprefix;
    __shared__ int skrem;
    __shared__ int nsel;
    __shared__ unsigned selb[KK];
    __shared__ int seli[KK];
    __shared__ float redg[4][NB];

    const int t = threadIdx.x;

    if (blockIdx.x >= NB) {
        // ---------- GEMV path: q[b,row] = dot(hidden[b,:], Wq[row,:]) ----------
        const int row = blockIdx.x - NB;
        const float4* wr = (const float4*)(Wq + (size_t)row * DIM);
        float acc[NB];
#pragma unroll
        for (int b = 0; b < NB; ++b) acc[b] = 0.f;
        for (int c = t; c < DIM / 4; c += 256) {
            float4 w = wr[c];
#pragma unroll
            for (int b = 0; b < NB; ++b) {
                float4 xv = ((const float4*)(hidden + (size_t)b * DIM))[c];
                acc[b] += w.x * xv.x + w.y * xv.y + w.z * xv.z + w.w * xv.w;
            }
        }
        const int lane = t & 63, wv = t >> 6;
#pragma unroll
        for (int b = 0; b < NB; ++b) {
            float vsum = acc[b];
            for (int o = 32; o > 0; o >>= 1) vsum += __shfl_down(vsum, o);
            if (lane == 0) redg[wv][b] = vsum;
        }
        __syncthreads();
        if (t < NB) q[(size_t)t * DIM + row] = redg[0][t] + redg[1][t] + redg[2][t] + redg[3][t];
        return;
    }

    // ---------- top-k path ----------
    const int b = blockIdx.x;
    const float* ip = imp + (size_t)b * S_TOK;
    for (int i = t; i < S_TOK; i += 256) {
        unsigned u = __float_as_uint(ip[i]);
        // monotone map: order of mapped bits == order of float values
        u = (u & 0x80000000u) ? ~u : (u | 0x80000000u);
        mb[i] = u;
    }
    if (t == 0) { sprefix = 0u; skrem = KK; nsel = 0; }
    __syncthreads();

    // radix-256 select: find bit pattern T of the 128th largest value
    for (int shift = 24; shift >= 0; shift -= 8) {
        hist[t] = 0;
        __syncthreads();
        const unsigned pfx = sprefix;
        const int krem = skrem;
        if (shift == 24) {
            // pass 1: values cluster into ~2 exponent bins -> ballot-aggregate
            // per distinct bin instead of same-address atomic pile-up.
            for (int i = t; i < S_TOK; i += 256) {
                int bin = mb[i] >> 24;
                unsigned long long rem = __ballot(1);
                while (rem) {
                    int fl = (int)__builtin_ctzll(rem);
                    int fbin = __shfl(bin, fl);
                    unsigned long long match = __ballot(bin == fbin);
                    if ((t & 63) == fl) atomicAdd(&hist[fbin], (int)__popcll(match));
                    rem &= ~match;
                }
            }
        } else {
            const unsigned pmask = 0xFFFFFFFFu << (shift + 8);
            for (int i = t; i < S_TOK; i += 256) {
                unsigned u = mb[i];
                if ((u & pmask) == pfx) atomicAdd(&hist[(u >> shift) & 255], 1);
            }
        }
        __syncthreads();
        // wave 0: parallel descending-bin scan (replaces serial t==0 scan).
        if (t < 64) {
            int4 h4 = *(const int4*)&hist[252 - 4 * t];          // bins 252-4t .. 255-4t
            int h0 = h4.w, h1 = h4.z, h2 = h4.y, h3 = h4.x;      // descending-bin order
            int c0 = h0, c1 = c0 + h1, c2 = c1 + h2, c3 = c2 + h3;
            int inc = c3;
#pragma unroll
            for (int o = 1; o < 64; o <<= 1) {
                int y = __shfl_up(inc, o);
                if (t >= o) inc += y;
            }
            int excl = inc - c3;                                  // count in strictly higher bins
            int cand = -1, before = 0;
            if      (excl + c0 >= krem) { cand = 0; before = excl; }
            else if (excl + c1 >= krem) { cand = 1; before = excl + c0; }
            else if (excl + c2 >= krem) { cand = 2; before = excl + c1; }
            else if (excl + c3 >= krem) { cand = 3; before = excl + c2; }
            unsigned long long ball = __ballot(cand >= 0);
            int win = (int)__builtin_ctzll(ball);                 // smallest p == largest bin
            if (t == win) {
                int p = 4 * t + cand;
                sprefix = pfx | ((unsigned)(255 - p) << shift);
                skrem = krem - before;
            }
        }
        __syncthreads();
    }
    const unsigned T = sprefix;

    // collect strictly-greater (unordered; sorted later)
    for (int i = t; i < S_TOK; i += 256) {
        unsigned u = mb[i];
        if (u > T) {
            int p = atomicAdd(&nsel, 1);
            selb[p] = u; seli[p] = i;
        }
    }
    __syncthreads();
    const int g = nsel;
    const int r = KK - g;          // >= 1 by construction

    // wave 0: ordered scan collects the r smallest-index ties (exact semantics,
    // replaces the 512-element bitonic sort).
    if (t < 64) {
        int found = 0;
        for (int base0 = 0; base0 < S_TOK && found < r; base0 += 64) {
            bool is_tie = (mb[base0 + t] == T);
            unsigned long long ball = __ballot(is_tie);
            int pos = (int)__popcll(ball & ((1ull << t) - 1ull));
            if (is_tie && found + pos < r) {
                selb[g + found + pos] = T;
                seli[g + found + pos] = base0 + t;
            }
            found += (int)__popcll(ball);
        }
    }
    __syncthreads();

    // bitonic sort 128 selected: value descending, index ascending
    for (int ksz = 2; ksz <= KK; ksz <<= 1) {
        for (int j = ksz >> 1; j > 0; j >>= 1) {
            if (t < KK) {
                int i = t, l = i ^ j;
                if (l > i) {
                    bool up = ((i & ksz) == 0);
                    unsigned ab = selb[i], cb = selb[l];
                    int ai = seli[i], ci = seli[l];
                    bool aFirst = (ab > cb) || (ab == cb && ai < ci);
                    if (up ? !aFirst : aFirst) {
                        selb[i] = cb; selb[l] = ab;
                        seli[i] = ci; seli[l] = ai;
                    }
                }
            }
            __syncthreads();
        }
    }
    if (t < KK) topk[b * KK + t] = seli[t];
}

// ---------------- Kernel 3: pruned attention, 256 threads per (b,h) ----------------
__global__ __launch_bounds__(256) void attn_kernel(const float* __restrict__ q,
                                                   const float* __restrict__ k,
                                                   const float* __restrict__ v,
                                                   const int* __restrict__ topk,
                                                   float* __restrict__ ctx,
                                                   float* __restrict__ probs_out) {
    const int bh = blockIdx.x;
    const int b = bh >> 5, h = bh & 31, kvh = h >> 2;
    const int t = threadIdx.x;   // 256 threads

    __shared__ float qs[DH];
    __shared__ float scs[KK];
    __shared__ float ps[KK];
    __shared__ int idxs[KK];
    __shared__ float red2[2];
    __shared__ float red3[2];
    __shared__ float ctxpart[DH];

    if (t < DH) qs[t] = q[(size_t)(b * HQ + h) * DH + t] * 0.088388347648318447f; // 1/sqrt(128)
    if (t < KK) idxs[t] = topk[b * KK + t];
    __syncthreads();

    // scores: 2 threads per token, each does a 64-dim half-dot
    {
        const int tok = t >> 1, half = t & 1;
        const float4* k4 = (const float4*)(k + ((size_t)(b * HKV + kvh) * S_TOK + idxs[tok]) * DH + half * 64);
        float sc = 0.f;
#pragma unroll
        for (int d4 = 0; d4 < 16; ++d4) {
            float4 kv = k4[d4];
            int d0 = half * 64 + d4 * 4;
            sc += qs[d0] * kv.x + qs[d0 + 1] * kv.y + qs[d0 + 2] * kv.z + qs[d0 + 3] * kv.w;
        }
        sc += __shfl_xor(sc, 1);             // adjacent lanes = two halves of same token
        if (half == 0) scs[tok] = sc;
    }
    __syncthreads();

    // softmax over 128 tokens (threads 0..127 hold one token each)
    float sc = (t < KK) ? scs[t] : -3.4e38f;
    float m = sc;
    for (int o = 32; o > 0; o >>= 1) m = fmaxf(m, __shfl_down(m, o));
    if (t < KK && (t & 63) == 0) red2[t >> 6] = m;
    __syncthreads();
    const float mx = fmaxf(red2[0], red2[1]);
    float p = (t < KK) ? expf(sc - mx) : 0.f;
    float sm = p;
    for (int o = 32; o > 0; o >>= 1) sm += __shfl_down(sm, o);
    if (t < KK && (t & 63) == 0) red3[t >> 6] = sm;
    __syncthreads();
    const float tot = red3[0] + red3[1];
    if (t < KK) {
        p /= tot;
        ps[t] = p;
        probs_out[(size_t)(b * HQ + h) * KK + t] = p;
    }
    __syncthreads();

    // PV: thread (d = t&127, grp = t>>7) accumulates 64 tokens; LDS combine.
    {
        const int d = t & (DH - 1), grp = t >> 7;
        const float* vbase = v + (size_t)(b * HKV + kvh) * S_TOK * DH;
        float acc = 0.f;
        const int s0 = grp * 64;
#pragma unroll 4
        for (int s2 = s0; s2 < s0 + 64; ++s2) {
            acc += ps[s2] * vbase[(size_t)idxs[s2] * DH + d];
        }
        if (grp == 1) ctxpart[d] = acc;
        __syncthreads();
        if (grp == 0) ctx[(size_t)(b * HQ + h) * DH + d] = acc + ctxpart[d];
    }
}

// ---------------- Kernel 4: batch-8 GEMV  y[b,row] = dot(x[b,:], W[row,:]) ----------------
__global__ __launch_bounds__(256) void gemv_b8(const float* __restrict__ W,
                                               const float* __restrict__ x,
                                               float* __restrict__ y) {
    const int row = blockIdx.x;
    const int t = threadIdx.x;
    const float4* wr = (const float4*)(W + (size_t)row * DIM);
    float acc[NB];
#pragma unroll
    for (int b = 0; b < NB; ++b) acc[b] = 0.f;
    for (int c = t; c < DIM / 4; c += 256) {
        float4 w = wr[c];
#pragma unroll
        for (int b = 0; b < NB; ++b) {
            float4 xv = ((const float4*)(x + (size_t)b * DIM))[c];
            acc[b] += w.x * xv.x + w.y * xv.y + w.z * xv.z + w.w * xv.w;
        }
    }
    __shared__ float red[4][NB];
    const int lane = t & 63, wv = t >> 6;
#pragma unroll
    for (int b = 0; b < NB; ++b) {
        float vsum = acc[b];
        for (int o = 32; o > 0; o >>= 1) vsum += __shfl_down(vsum, o);
        if (lane == 0) red[wv][b] = vsum;
    }
    __syncthreads();
    if (t < NB) {
        y[(size_t)t * DIM + row] = red[0][t] + red[1][t] + red[2][t] + red[3][t];
    }
}

// ---------------- launcher ----------------
extern "C" void kernel_launch(void* const* d_in, const int* in_sizes, int n_in,
                              void* d_out, int out_size, void* d_ws, size_t ws_size,
                              hipStream_t stream) {
    const float* hidden = (const float*)d_in[0];   // [8,1,4096]
    const float* attn_w = (const float*)d_in[1];   // [8,32,1,8192]
    const float* k      = (const float*)d_in[2];   // [8,8,8192,128]
    const float* v      = (const float*)d_in[3];   // [8,8,8192,128]
    const float* Wq     = (const float*)d_in[4];   // [4096,4096]
    const float* Wo     = (const float*)d_in[5];   // [4096,4096]

    float* out   = (float*)d_out;                  // [8,4096]
    float* probs = out + NB * DIM;                 // [8,32,1,128]

    char* ws = (char*)d_ws;
    float* imp  = (float*)ws;                       // 8*8192*4   = 262144 B
    int*   topk = (int*)(ws + 262144);              // 8*128*4    =   4096 B
    float* q    = (float*)(ws + 266240);            // 8*4096*4   = 131072 B
    float* ctx  = (float*)(ws + 397312);            // 8*4096*4   = 131072 B

    importance_kernel<<<(NB * S_TOK) / 256, 256, 0, stream>>>(attn_w, imp);
    // fused: blocks 0..7 do top-k (depends on imp); blocks 8..8+4095 do q GEMV
    // (depends only on hidden) -> top-k latency hides under the Wq read.
    topk_gemvq_kernel<<<NB + DIM, 256, 0, stream>>>(imp, topk, Wq, hidden, q);
    attn_kernel<<<NB * HQ, 256, 0, stream>>>(q, k, v, topk, ctx, probs);
    gemv_b8<<<DIM, 256, 0, stream>>>(Wo, ctx, out);
}